// Round 1
// baseline (2282.142 us; speedup 1.0000x reference)
//
#include <hip/hip_runtime.h>

typedef __attribute__((ext_vector_type(8))) short bf16x8;
typedef __attribute__((ext_vector_type(4))) float f32x4;
typedef __attribute__((ext_vector_type(4))) unsigned short u16x4;

__device__ __forceinline__ unsigned short f2b(float f) {
    unsigned u = __builtin_bit_cast(unsigned, f);
    u += 0x7fffu + ((u >> 16) & 1u);   // round-to-nearest-even
    return (unsigned short)(u >> 16);
}

__global__ void zero_f32(float* __restrict__ p, long total) {
    long i = ((long)blockIdx.x * blockDim.x + threadIdx.x) * 4;
    if (i + 3 < total) {
        *(f32x4*)(p + i) = (f32x4){0.f, 0.f, 0.f, 0.f};
    } else {
        for (long t = i; t < total; ++t) p[t] = 0.f;
    }
}

__global__ void cvt_bf16(const float* __restrict__ x, unsigned short* __restrict__ o, long total) {
    long i = ((long)blockIdx.x * blockDim.x + threadIdx.x) * 4;
    if (i >= total) return;
    f32x4 v = *(const f32x4*)(x + i);
    u16x4 r;
#pragma unroll
    for (int t = 0; t < 4; ++t) r[t] = f2b(v[t]);
    *(u16x4*)(o + i) = r;
}

// Rearrange W [K,128,128] f32 into MFMA-B-fragment-major bf16:
// Wb[k][frag f=kk*8+c][lane][j] = W[k][cin=kk*32+(lane>>4)*8+j][cout=c*16+(lane&15)]
__global__ void prep_w(const float* __restrict__ W1, const float* __restrict__ W2,
                       unsigned short* __restrict__ Wb1, unsigned short* __restrict__ Wb2,
                       int kelems /* K*16384 */) {
    int tid = blockIdx.x * 256 + threadIdx.x;
    if (tid >= 2 * kelems) return;
    int which = (tid >= kelems) ? 1 : 0;
    int rem = which ? (tid - kelems) : tid;
    int k = rem >> 14;
    int r2 = rem & 16383;
    int f = r2 >> 9;
    int lane = (r2 >> 3) & 63;
    int j = r2 & 7;
    int kk = f >> 3, c = f & 7;
    int cin = kk * 32 + (lane >> 4) * 8 + j;
    int cout = c * 16 + (lane & 15);
    const float* W = which ? W2 : W1;
    unsigned short* Wb = which ? Wb2 : Wb1;
    Wb[rem] = f2b(W[(size_t)k * 16384 + cin * 128 + cout]);
}

// One k-slice of the sparse conv: out[idx_out[k][m]] += xin[idx_in[k][m]] @ W[k]
// block = 256 threads (4 waves), BM = 128 gathered rows, full 128 output cols.
__global__ __launch_bounds__(256) void conv_mfma(
    const unsigned short* __restrict__ xin,   // [n,128] bf16
    const unsigned short* __restrict__ Wb,    // [K][32 frags][64 lanes][8] bf16
    const int* __restrict__ idx_in,           // [K,n]
    const int* __restrict__ idx_out,          // [K,n]
    float* __restrict__ out,                  // [n,128] f32 accumulator
    int n)
{
    __shared__ unsigned short wlds[16384];    // 32 KB: whole W[k] in frag layout
    const int k = blockIdx.y;
    const int m0 = blockIdx.x * 128;

    {   // stage W[k] -> LDS, coalesced 16B per lane
        const bf16x8* src = (const bf16x8*)(Wb + (size_t)k * 16384);
        bf16x8* dst = (bf16x8*)wlds;
        for (int i = threadIdx.x; i < 2048; i += 256) dst[i] = src[i];
    }
    __syncthreads();

    const int wave = threadIdx.x >> 6;
    const int lane = threadIdx.x & 63;
    const int kg = lane >> 4;     // 0..3
    const int l15 = lane & 15;

    const int* iin  = idx_in  + (size_t)k * n;
    const int* iout = idx_out + (size_t)k * n;
    const int mbase = m0 + wave * 32;

    // gathered A row indices for the two 16-row strips (clamped; masked at store)
    int arow0, arow1;
    { int m = mbase + l15;      arow0 = (m < n) ? iin[m] : 0; }
    { int m = mbase + 16 + l15; arow1 = (m < n) ? iin[m] : 0; }

    f32x4 acc[2][8];
#pragma unroll
    for (int s = 0; s < 2; ++s)
#pragma unroll
        for (int c = 0; c < 8; ++c) acc[s][c] = (f32x4){0.f, 0.f, 0.f, 0.f};

#pragma unroll
    for (int kk = 0; kk < 4; ++kk) {
        // A frag: lane holds xin[row=l15][k=kk*32+kg*8 .. +8]
        bf16x8 a0 = *(const bf16x8*)(xin + (size_t)arow0 * 128 + kk * 32 + kg * 8);
        bf16x8 a1 = *(const bf16x8*)(xin + (size_t)arow1 * 128 + kk * 32 + kg * 8);
#pragma unroll
        for (int c = 0; c < 8; ++c) {
            bf16x8 b = *(const bf16x8*)(wlds + ((kk * 8 + c) * 64 + lane) * 8);
            acc[0][c] = __builtin_amdgcn_mfma_f32_16x16x32_bf16(a0, b, acc[0][c], 0, 0, 0);
            acc[1][c] = __builtin_amdgcn_mfma_f32_16x16x32_bf16(a1, b, acc[1][c], 0, 0, 0);
        }
    }

    // scatter-add: C/D layout col=lane&15, row=(lane>>4)*4+reg
#pragma unroll
    for (int s = 0; s < 2; ++s) {
#pragma unroll
        for (int j = 0; j < 4; ++j) {
            int m = mbase + s * 16 + kg * 4 + j;
            if (m < n) {
                long orow = iout[m];
                float* dst = out + orow * 128 + l15;
#pragma unroll
                for (int c = 0; c < 8; ++c)
                    atomicAdd(dst + c * 16, acc[s][c][j]);
            }
        }
    }
}

// per-channel sum & sumsq over rows, atomically accumulated into stats[0..127], stats[128..255]
__global__ void bn_stats(const float* __restrict__ h, float* __restrict__ stats, int n) {
    const int c = threadIdx.x & 127;
    const int half = threadIdx.x >> 7;
    const int r0 = blockIdx.x * 256;
    const int rend = min(r0 + 256, n);
    float s = 0.f, s2 = 0.f;
    for (int r = r0 + half; r < rend; r += 2) {
        float v = h[(size_t)r * 128 + c];
        s += v; s2 += v * v;
    }
    __shared__ float ls[256], ls2[256];
    ls[threadIdx.x] = s; ls2[threadIdx.x] = s2;
    __syncthreads();
    if (half == 0) {
        atomicAdd(&stats[c], ls[c] + ls[128 + c]);
        atomicAdd(&stats[128 + c], ls2[c] + ls2[128 + c]);
    }
}

__global__ void bn_finalize(float* stats, const float* __restrict__ g,
                            const float* __restrict__ b, float inv_n) {
    int c = threadIdx.x;  // 128 threads
    float mu = stats[c] * inv_n;
    float var = fmaxf(stats[128 + c] * inv_n - mu * mu, 0.f);
    float sc = g[c] * rsqrtf(var + 1e-5f);
    stats[256 + c] = sc;
    stats[384 + c] = b[c] - mu * sc;
}

__global__ void bn_relu_bf16(const float* __restrict__ h, const float* __restrict__ stats,
                             unsigned short* __restrict__ hb, long total) {
    long i = ((long)blockIdx.x * 256 + threadIdx.x) * 4;
    if (i >= total) return;
    int c = (int)(i & 127);
    f32x4 v = *(const f32x4*)(h + i);
    u16x4 r;
#pragma unroll
    for (int t = 0; t < 4; ++t) {
        float y = fmaxf(v[t] * stats[256 + c + t] + stats[384 + c + t], 0.f);
        r[t] = f2b(y);
    }
    *(u16x4*)(hb + i) = r;
}

__global__ void bn_res_relu(float* __restrict__ out, const float* __restrict__ stats,
                            const float* __restrict__ x, long total) {
    long i = ((long)blockIdx.x * 256 + threadIdx.x) * 4;
    if (i >= total) return;
    int c = (int)(i & 127);
    f32x4 h = *(const f32x4*)(out + i);
    f32x4 xv = *(const f32x4*)(x + i);
    f32x4 r;
#pragma unroll
    for (int t = 0; t < 4; ++t)
        r[t] = fmaxf(h[t] * stats[256 + c + t] + stats[384 + c + t] + xv[t], 0.f);
    *(f32x4*)(out + i) = r;
}

extern "C" void kernel_launch(void* const* d_in, const int* in_sizes, int n_in,
                              void* d_out, int out_size, void* d_ws, size_t ws_size,
                              hipStream_t stream) {
    const float* x  = (const float*)d_in[0];
    const float* W1 = (const float*)d_in[1];
    const float* g1 = (const float*)d_in[2];
    const float* b1 = (const float*)d_in[3];
    const float* W2 = (const float*)d_in[4];
    const float* g2 = (const float*)d_in[5];
    const float* b2 = (const float*)d_in[6];
    const int* idx_in  = (const int*)d_in[7];
    const int* idx_out = (const int*)d_in[8];

    const int n = in_sizes[0] / 128;          // 100000
    const int K = in_sizes[1] / 16384;        // 27
    const long total = (long)n * 128;
    float* out = (float*)d_out;

    // workspace layout
    char* ws = (char*)d_ws;
    unsigned short* xb  = (unsigned short*)ws;                       // n*128 bf16
    unsigned short* hb  = (unsigned short*)(ws + (size_t)total * 2); // n*128 bf16
    unsigned short* Wb1 = (unsigned short*)(ws + (size_t)total * 4);
    unsigned short* Wb2 = Wb1 + (size_t)K * 16384;
    float* stats = (float*)(Wb2 + (size_t)K * 16384);                // 2 x 512 f32

    const dim3 b256(256);
    const int gApply = (int)((total / 4 + 255) / 256);   // 12500
    const dim3 cgrid((n + 127) / 128, K);
    const int kelems = K * 16384;

    hipLaunchKernelGGL(zero_f32, dim3(gApply), b256, 0, stream, out, total);
    hipLaunchKernelGGL(zero_f32, dim3(1), b256, 0, stream, stats, (long)1024);
    hipLaunchKernelGGL(cvt_bf16, dim3(gApply), b256, 0, stream, x, xb, total);
    hipLaunchKernelGGL(prep_w, dim3((2 * kelems + 255) / 256), b256, 0, stream,
                       W1, W2, Wb1, Wb2, kelems);

    // conv1 -> out (as f32 accumulator)
    hipLaunchKernelGGL(conv_mfma, cgrid, b256, 0, stream, xb, Wb1, idx_in, idx_out, out, n);
    hipLaunchKernelGGL(bn_stats, dim3((n + 255) / 256), b256, 0, stream, out, stats, n);
    hipLaunchKernelGGL(bn_finalize, dim3(1), dim3(128), 0, stream, stats, g1, b1, 1.0f / n);
    hipLaunchKernelGGL(bn_relu_bf16, dim3(gApply), b256, 0, stream, out, stats, hb, total);

    // conv2 -> out (re-zeroed)
    hipLaunchKernelGGL(zero_f32, dim3(gApply), b256, 0, stream, out, total);
    hipLaunchKernelGGL(conv_mfma, cgrid, b256, 0, stream, hb, Wb2, idx_in, idx_out, out, n);
    hipLaunchKernelGGL(bn_stats, dim3((n + 255) / 256), b256, 0, stream, out, stats + 512, n);
    hipLaunchKernelGGL(bn_finalize, dim3(1), dim3(128), 0, stream, stats + 512, g2, b2, 1.0f / n);
    hipLaunchKernelGGL(bn_res_relu, dim3(gApply), b256, 0, stream, out, stats + 512, x, total);
}